// Round 7
// baseline (766.974 us; speedup 1.0000x reference)
//
#include <hip/hip_runtime.h>
#include <stdint.h>
#include <math.h>

// ---------------- problem sizes ----------------
#define NB   64
#define LL   2000
#define CIN  4
#define NF   256
#define KW   13
#define NOUT 500
#define NH   8
#define DH   64
#define DMID 100
#define NCLS 2

// ---------------- ws layout (byte offsets) ----------------
#define OFF_PSUM   0        // [64][256]
#define OFF_PSQ    16384    // [64][256]
#define OFF_SCALE  32768    // [256]
#define OFF_SHIFT  33024    // [256]
#define OFF_PART   33280    // [64][8][100]
#define BOFF_WT    337920ull                  // W_T bf16 [24][64 d][256 f] = 786,432
#define BOFF_WMT   1124352ull                 // WmT bf16 [112 c][512 k] = 114,688
#define BOFF_Q     1239040ull                 // q bf16 [64][8][500][64] = 32,768,000
#define BOFF_K     34007040ull                // k bf16 same
#define BOFF_VT    66775040ull                // v^T bf16 [64][8][64 d][512 n] = 33,554,432
#define BOFF_YM    100329472ull               // ymax_T bf16 [64][500][256] = 16,384,000
#define BOFF_O     BOFF_YM                    // o bf16 [64][500][512] (aliases ymax_T span)
#define WS_NEED    133097472ull               // < 128 MiB

// ---------------- bf16 helpers (RNE) ----------------
__device__ __forceinline__ float blo(uint32_t u) { return __uint_as_float(u << 16); }
__device__ __forceinline__ float bhi(uint32_t u) { return __uint_as_float(u & 0xFFFF0000u); }
__device__ __forceinline__ uint32_t f2bf1(float f) {
  uint32_t x = __float_as_uint(f);
  return (x + 0x7FFFu + ((x >> 16) & 1u)) >> 16;
}
__device__ __forceinline__ uint32_t pack2(float a, float b) {
  return f2bf1(a) | (f2bf1(b) << 16);
}

typedef short bf16x8 __attribute__((ext_vector_type(8)));
typedef float f32x4  __attribute__((ext_vector_type(4)));
union UB { uint4 u; bf16x8 v; };

// XOR swizzle for [rows][64 bf16] LDS tiles (128 B rows) — k_attn.
__device__ __forceinline__ int swz(int row, int colElem) {
  return row * 128 + ((colElem * 2) ^ ((row & 7) << 4));
}
// XOR swizzle for [64 n][256 f] bf16 A-tile (512 B rows) — k_qkv.
// 16B slot index (f>>3, 0..31) gets its low 3 bits XORed with (row&7).
__device__ __forceinline__ int addrA(int row, int f) {
  return row * 512 + (((f >> 3) ^ (row & 7)) << 4) + ((f & 7) * 2);
}

// =====================================================================
// Kernel 0: weight prep.
// blocks 0..23: Wq/Wk/Wv fp32 [8][256 f][64 d] -> bf16 WT[g][64 d][256 f]
// block 24:     Wm fp32 [512 k][100 c] -> bf16 WmT[112 c][512 k] (c-padded 0)
// =====================================================================
__global__ void k_prep(const float* __restrict__ Wq, const float* __restrict__ Wk,
                       const float* __restrict__ Wv, const float* __restrict__ Wm,
                       uint16_t* __restrict__ WT, uint16_t* __restrict__ WmT) {
  const int g = blockIdx.x;
  if (g < 24) {
    const int which = g >> 3, h = g & 7;
    const float* W = (which == 0 ? Wq : which == 1 ? Wk : Wv) + (size_t)h * NF * DH;
    uint16_t* dst = WT + (size_t)g * DH * NF;
    for (int idx = threadIdx.x; idx < NF * DH; idx += 256) {
      const int f = idx >> 6, d = idx & 63;
      dst[d * NF + f] = (uint16_t)f2bf1(W[idx]);
    }
  } else {
    for (int idx = threadIdx.x; idx < 112 * 512; idx += 256) {
      const int c = idx >> 9, k = idx & 511;
      WmT[idx] = (c < DMID) ? (uint16_t)f2bf1(Wm[k * DMID + c]) : (uint16_t)0;
    }
  }
}

// =====================================================================
// Kernel 1: conv1d + per-channel sum/sumsq (pre-BN) + maxpool(4), fused.
// Writes pre-BN pooled max TRANSPOSED as bf16 ymax_T[b][n][256 f].
// BN+ReLU commute with max (scale>0), applied in k_qkv staging.
// =====================================================================
__global__ __launch_bounds__(512) void k_conv(const float* __restrict__ x,
                                              const float* __restrict__ cw,
                                              uint16_t* __restrict__ ymaxT,
                                              float* __restrict__ psum,
                                              float* __restrict__ psq) {
  const int b = blockIdx.x;
  const int fg = blockIdx.y;
  const int tid = threadIdx.x;
  const int n = tid;                // pooled position
  const bool act = (n < NOUT);
  const float* xb = x + (size_t)b * (LL * CIN);

  float4 xw[16];
#pragma unroll
  for (int i = 0; i < 16; ++i) {
    const int p = 4 * n - 6 + i;
    if (act && p >= 0 && p < LL)
      xw[i] = *(const float4*)(xb + (size_t)p * CIN);
    else
      xw[i] = make_float4(0.f, 0.f, 0.f, 0.f);
  }

  __shared__ float redS[8][16];
  __shared__ float redQ[8][16];
  const int wave = tid >> 6, lane = tid & 63;
  uint32_t pw[8];
  float prev = 0.f;

  for (int fi = 0; fi < 16; ++fi) {
    const int f = fg * 16 + fi;
    const float* w = cw + (size_t)f * (CIN * KW);
    float wr[4][13];
#pragma unroll
    for (int c = 0; c < 4; ++c)
#pragma unroll
      for (int k = 0; k < 13; ++k) wr[c][k] = w[c * 13 + k];

    float a0 = 0.f, a1 = 0.f, a2 = 0.f, a3 = 0.f;
#pragma unroll
    for (int k = 0; k < 13; ++k) {
      const float4 p0 = xw[k + 0];
      const float4 p1 = xw[k + 1];
      const float4 p2 = xw[k + 2];
      const float4 p3 = xw[k + 3];
      a0 += wr[0][k] * p0.x + wr[1][k] * p0.y + wr[2][k] * p0.z + wr[3][k] * p0.w;
      a1 += wr[0][k] * p1.x + wr[1][k] * p1.y + wr[2][k] * p1.z + wr[3][k] * p1.w;
      a2 += wr[0][k] * p2.x + wr[1][k] * p2.y + wr[2][k] * p2.z + wr[3][k] * p2.w;
      a3 += wr[0][k] * p3.x + wr[1][k] * p3.y + wr[2][k] * p3.z + wr[3][k] * p3.w;
    }
    const float pm = fmaxf(fmaxf(a0, a1), fmaxf(a2, a3));
    if (fi & 1) pw[fi >> 1] = pack2(prev, pm); else prev = pm;

    float s  = act ? (a0 + a1 + a2 + a3) : 0.f;
    float q2 = act ? (a0 * a0 + a1 * a1 + a2 * a2 + a3 * a3) : 0.f;
#pragma unroll
    for (int off = 32; off >= 1; off >>= 1) {
      s  += __shfl_xor(s,  off, 64);
      q2 += __shfl_xor(q2, off, 64);
    }
    if (lane == 0) { redS[wave][fi] = s; redQ[wave][fi] = q2; }
  }
  if (act) {
    uint16_t* dst = ymaxT + ((size_t)b * NOUT + n) * NF + fg * 16;
    uint4 s0 = make_uint4(pw[0], pw[1], pw[2], pw[3]);
    uint4 s1 = make_uint4(pw[4], pw[5], pw[6], pw[7]);
    *(uint4*)dst = s0;
    *(uint4*)(dst + 8) = s1;
  }
  __syncthreads();
  if (tid < 16) {
    float s = 0.f;
#pragma unroll
    for (int wv = 0; wv < 8; ++wv) s += redS[wv][tid];
    psum[b * NF + fg * 16 + tid] = s;
  } else if (tid < 32) {
    float s = 0.f;
#pragma unroll
    for (int wv = 0; wv < 8; ++wv) s += redQ[wv][tid - 16];
    psq[b * NF + fg * 16 + (tid - 16)] = s;
  }
}

// =====================================================================
// Kernel 2: fold BN batch stats into per-channel scale/shift.
// =====================================================================
__global__ void k_stats(const float* __restrict__ psum, const float* __restrict__ psq,
                        const float* __restrict__ gamma, const float* __restrict__ beta,
                        float* __restrict__ scale, float* __restrict__ shift) {
  const int f = threadIdx.x;
  float s = 0.f, q = 0.f;
  for (int b = 0; b < NB; ++b) { s += psum[b * NF + f]; q += psq[b * NF + f]; }
  const float inv = 1.0f / (float)(NB * LL);
  const float mean = s * inv;
  const float var = q * inv - mean * mean;
  const float sc = gamma[f] * rsqrtf(var + 1e-5f);
  scale[f] = sc;
  shift[f] = beta[f] - mean * sc;
}

// =====================================================================
// Kernel 3 (v2): QKV projection, MFMA, LDS A-tile.
// grid (3 which, 8 nt, 64 b), block 256 = 4 waves; wave = 64n x 64d for
// h = {wv, wv+4}.  Staging: 64x256 h-tile (BN+ReLU fused, XOR-swizzled,
// 32 KB).  Per K-chunk: 4 W-frags (L2-hot WT) + 4 h-frags (LDS) -> 16 MFMA.
// Stores: operand-SWAPPED mfma for q/k (regs run along d -> packed 8B
// stores to [n][d]); normal order for v (regs along n -> packed 8B stores
// to vbT[d][n]).  No transpose buffers, no 2B scatters.
// =====================================================================
__global__ __launch_bounds__(256, 4) void k_qkv(const uint16_t* __restrict__ ymaxT,
     const float* __restrict__ scale, const float* __restrict__ shift,
     const uint16_t* __restrict__ WT,
     const float* __restrict__ bq, const float* __restrict__ bk, const float* __restrict__ bv,
     uint16_t* __restrict__ qb, uint16_t* __restrict__ kb, uint16_t* __restrict__ vbT) {
  const int which = blockIdx.x;
  const int nt = blockIdx.y;
  const int b  = blockIdx.z;
  const int tid = threadIdx.x;
  const int wv = tid >> 6, l = tid & 63;
  const int lg = l >> 4, lq = l & 15;
  const int n0 = nt * 64;

  __shared__ char smem[32768 + 2048];
  char* ldsA = smem;
  float* biasLds = (float*)(smem + 32768);

  // ---- stage A-tile (BN+ReLU fused) + bias ----
  {
    const int col16 = tid & 31;
    const int f0 = col16 * 8;
    const float4 s0 = *(const float4*)(scale + f0);
    const float4 s1 = *(const float4*)(scale + f0 + 4);
    const float4 h0 = *(const float4*)(shift + f0);
    const float4 h1 = *(const float4*)(shift + f0 + 4);
#pragma unroll
    for (int p = 0; p < 8; ++p) {
      const int row = p * 8 + (tid >> 5);
      const int n = min(n0 + row, NOUT - 1);
      const uint4 u = *(const uint4*)(ymaxT + ((size_t)b * NOUT + n) * NF + f0);
      uint4 o;
      o.x = pack2(fmaxf(s0.x * blo(u.x) + h0.x, 0.f), fmaxf(s0.y * bhi(u.x) + h0.y, 0.f));
      o.y = pack2(fmaxf(s0.z * blo(u.y) + h0.z, 0.f), fmaxf(s0.w * bhi(u.y) + h0.w, 0.f));
      o.z = pack2(fmaxf(s1.x * blo(u.z) + h1.x, 0.f), fmaxf(s1.y * bhi(u.z) + h1.y, 0.f));
      o.w = pack2(fmaxf(s1.z * blo(u.w) + h1.z, 0.f), fmaxf(s1.w * bhi(u.w) + h1.w, 0.f));
      *(uint4*)(ldsA + addrA(row, f0)) = o;
    }
    const float* biasW = (which == 0 ? bq : which == 1 ? bk : bv);
    biasLds[tid] = biasW[tid];
    biasLds[tid + 256] = biasW[tid + 256];
  }
  __syncthreads();

  for (int hi = 0; hi < 2; ++hi) {
    const int h = wv + hi * 4;
    const uint16_t* WTg = WT + (size_t)(which * 8 + h) * DH * NF;

    f32x4 acc[4][4] = {};   // q/k: [dt][s] ; v: [s][dt]
#pragma unroll
    for (int c = 0; c < 8; ++c) {
      const int f0 = c * 32 + lg * 8;
      UB wf[4], hf[4];
#pragma unroll
      for (int dt = 0; dt < 4; ++dt)
        wf[dt].u = *(const uint4*)(WTg + (size_t)(16 * dt + lq) * NF + f0);
#pragma unroll
      for (int s = 0; s < 4; ++s)
        hf[s].u = *(const uint4*)(ldsA + addrA(16 * s + lq, f0));
      if (which < 2) {
#pragma unroll
        for (int dt = 0; dt < 4; ++dt)
#pragma unroll
          for (int s = 0; s < 4; ++s)
            acc[dt][s] = __builtin_amdgcn_mfma_f32_16x16x32_bf16(wf[dt].v, hf[s].v, acc[dt][s], 0, 0, 0);
      } else {
#pragma unroll
        for (int s = 0; s < 4; ++s)
#pragma unroll
          for (int dt = 0; dt < 4; ++dt)
            acc[s][dt] = __builtin_amdgcn_mfma_f32_16x16x32_bf16(hf[s].v, wf[dt].v, acc[s][dt], 0, 0, 0);
      }
    }

    if (which < 2) {
      // D swapped: lane col = n = 16s+lq, reg rows = d = 16dt+4lg+r
      uint16_t* out = (which == 0 ? qb : kb) + (size_t)(b * NH + h) * NOUT * DH;
#pragma unroll
      for (int dt = 0; dt < 4; ++dt) {
        const int d0 = 16 * dt + 4 * lg;
        const float bb0 = biasLds[h * DH + d0 + 0];
        const float bb1 = biasLds[h * DH + d0 + 1];
        const float bb2 = biasLds[h * DH + d0 + 2];
        const float bb3 = biasLds[h * DH + d0 + 3];
#pragma unroll
        for (int s = 0; s < 4; ++s) {
          const int n = n0 + 16 * s + lq;
          if (n < NOUT) {
            uint2 w;
            w.x = pack2(acc[dt][s][0] + bb0, acc[dt][s][1] + bb1);
            w.y = pack2(acc[dt][s][2] + bb2, acc[dt][s][3] + bb3);
            *(uint2*)(out + (size_t)n * DH + d0) = w;
          }
        }
      }
    } else {
      // D normal: lane col = d = 16dt+lq, reg rows = n = 16s+4lg+r
      uint16_t* out = vbT + (size_t)(b * NH + h) * DH * 512;
#pragma unroll
      for (int s = 0; s < 4; ++s) {
        const int nb4 = n0 + 16 * s + 4 * lg;
        if (nb4 < NOUT) {
#pragma unroll
          for (int dt = 0; dt < 4; ++dt) {
            const int d = 16 * dt + lq;
            const float bb = biasLds[h * DH + d];
            uint2 w;
            w.x = pack2(acc[s][dt][0] + bb, acc[s][dt][1] + bb);
            w.y = pack2(acc[s][dt][2] + bb, acc[s][dt][3] + bb);
            *(uint2*)(out + (size_t)d * 512 + nb4) = w;
          }
        }
      }
    }
  }
}

// =====================================================================
// Kernel 4: fused attention, MFMA flash-style (unchanged, HW-validated R5).
// =====================================================================
__global__ __launch_bounds__(256, 4) void k_attn(const uint16_t* __restrict__ qb,
                                                 const uint16_t* __restrict__ kb,
                                                 const uint16_t* __restrict__ vbT,
                                                 uint16_t* __restrict__ ob) {
  const int qt = blockIdx.x;
  const int h  = blockIdx.y;
  const int b  = blockIdx.z;
  const int tid = threadIdx.x;
  const int wv = tid >> 6, l = tid & 63;
  const int lg = l >> 4, lq = l & 15;

  __shared__ char smem[24576];
  char* Ks = smem;                       // K tile  [64 key][64 d] bf16, swizzled
  char* Vs = smem + 8192;                // V^T tile [64 d][64 key] bf16, swizzled
  char* Ps = smem + 16384 + wv * 2048;   // P tile  [16 q][64 key] bf16, swizzled

  const size_t qkbase = (size_t)(b * NH + h) * NOUT * DH;
  const size_t vbase  = (size_t)(b * NH + h) * DH * 512;
  const int q0 = qt * 64 + wv * 16;

  bf16x8 qf[2];
  {
    const int qn = min(q0 + lq, NOUT - 1);
    const uint16_t* src = qb + qkbase + (size_t)qn * DH + lg * 8;
    UB t0, t1;
    t0.u = *(const uint4*)src;
    t1.u = *(const uint4*)(src + 32);
    qf[0] = t0.v; qf[1] = t1.v;
  }

  f32x4 oacc[4] = {};
  float m = -1e30f, lsum = 0.f;
  const int nq = q0 + lq;

  for (int kt = 0; kt < 8; ++kt) {
    const int kv0 = kt * 64;
    __syncthreads();
    {
      const int r = tid >> 2, cc = (tid & 3) * 16;
      const int kn = min(kv0 + r, NOUT - 1);
      const uint16_t* ksrc = kb + qkbase + (size_t)kn * DH + cc;
      uint4 ka = *(const uint4*)ksrc;
      uint4 kb4 = *(const uint4*)(ksrc + 8);
      *(uint4*)(Ks + swz(r, cc))     = ka;
      *(uint4*)(Ks + swz(r, cc + 8)) = kb4;
      const uint16_t* vsrc = vbT + vbase + (size_t)r * 512 + kv0 + cc;
      uint4 va = *(const uint4*)vsrc;
      uint4 vb4 = *(const uint4*)(vsrc + 8);
      *(uint4*)(Vs + swz(r, cc))     = va;
      *(uint4*)(Vs + swz(r, cc + 8)) = vb4;
    }
    __syncthreads();

    f32x4 sacc[4] = {};
#pragma unroll
    for (int c = 0; c < 2; ++c)
#pragma unroll
      for (int s = 0; s < 4; ++s) {
        UB kf;
        kf.u = *(const uint4*)(Ks + swz(16 * s + lq, 32 * c + 8 * lg));
        sacc[s] = __builtin_amdgcn_mfma_f32_16x16x32_bf16(kf.v, qf[c], sacc[s], 0, 0, 0);
      }

    float tmax = -1e30f;
#pragma unroll
    for (int s = 0; s < 4; ++s)
#pragma unroll
      for (int r = 0; r < 4; ++r) {
        const int nk = kv0 + 16 * s + 4 * lg + r;
        float val = sacc[s][r] * 0.125f -
                    (4.0f * fabsf((float)(nq - nk)) + 3.0f) * (1.0f / 1999.0f);
        if (nk >= NOUT) val = -1e30f;
        sacc[s][r] = val;
        tmax = fmaxf(tmax, val);
      }
    tmax = fmaxf(tmax, __shfl_xor(tmax, 16, 64));
    tmax = fmaxf(tmax, __shfl_xor(tmax, 32, 64));
    const float mnew = fmaxf(m, tmax);
    const float corr = __expf(m - mnew);
    m = mnew;
    float ls = 0.f;
#pragma unroll
    for (int s = 0; s < 4; ++s)
#pragma unroll
      for (int r = 0; r < 4; ++r) {
        const float pv = __expf(sacc[s][r] - mnew);
        sacc[s][r] = pv;
        ls += pv;
      }
    ls += __shfl_xor(ls, 16, 64);
    ls += __shfl_xor(ls, 32, 64);
    lsum = lsum * corr + ls;

#pragma unroll
    for (int s = 0; s < 4; ++s) {
      uint2 w;
      w.x = pack2(sacc[s][0], sacc[s][1]);
      w.y = pack2(sacc[s][2], sacc[s][3]);
      *(uint2*)(Ps + swz(lq, 16 * s + 4 * lg)) = w;
    }

    float cr[4];
#pragma unroll
    for (int r = 0; r < 4; ++r) cr[r] = __shfl(corr, 4 * lg + r, 64);
#pragma unroll
    for (int t = 0; t < 4; ++t)
#pragma unroll
      for (int r = 0; r < 4; ++r) oacc[t][r] *= cr[r];

#pragma unroll
    for (int c = 0; c < 2; ++c) {
      UB pf;
      pf.u = *(const uint4*)(Ps + swz(lq, 32 * c + 8 * lg));
#pragma unroll
      for (int t = 0; t < 4; ++t) {
        UB vf;
        vf.u = *(const uint4*)(Vs + swz(16 * t + lq, 32 * c + 8 * lg));
        oacc[t] = __builtin_amdgcn_mfma_f32_16x16x32_bf16(pf.v, vf.v, oacc[t], 0, 0, 0);
      }
    }
  }

  const float inv = 1.0f / lsum;
  float invr[4];
#pragma unroll
  for (int r = 0; r < 4; ++r) invr[r] = __shfl(inv, 4 * lg + r, 64);
#pragma unroll
  for (int t = 0; t < 4; ++t) {
    const int d = 16 * t + lq;
#pragma unroll
    for (int r = 0; r < 4; ++r) {
      const int nn = q0 + 4 * lg + r;
      if (nn < NOUT)
        ob[((size_t)b * NOUT + nn) * (NH * DH) + h * DH + d] =
            (uint16_t)f2bf1(oacc[t][r] * invr[r]);
    }
  }
}

// =====================================================================
// Kernel 5: m = relu(o @ Wm + bm); position-sum -> part (unchanged).
// =====================================================================
__global__ __launch_bounds__(256, 4) void k_mhl(const uint16_t* __restrict__ ob,
                                                const uint16_t* __restrict__ WmT,
                                                const float* __restrict__ bm,
                                                float* __restrict__ part) {
  const int nt = blockIdx.x;
  const int b  = blockIdx.y;
  const int tid = threadIdx.x;
  const int wv = tid >> 6, l = tid & 63;
  const int lg = l >> 4, lq = l & 15;
  const int n0 = nt * 64 + wv * 16;

  __shared__ float lfeat[4][112];

  f32x4 acc[7] = {};
  const int an = min(n0 + lq, NOUT - 1);
  const uint16_t* abase = ob + ((size_t)b * NOUT + an) * (NH * DH);

  for (int kc = 0; kc < 16; ++kc) {
    const int k0 = kc * 32 + lg * 8;
    UB a;
    a.u = *(const uint4*)(abase + k0);
#pragma unroll
    for (int t = 0; t < 7; ++t) {
      UB bfr;
      bfr.u = *(const uint4*)(WmT + (size_t)(16 * t + lq) * 512 + k0);
      acc[t] = __builtin_amdgcn_mfma_f32_16x16x32_bf16(a.v, bfr.v, acc[t], 0, 0, 0);
    }
  }

#pragma unroll
  for (int t = 0; t < 7; ++t) {
    const int c = 16 * t + lq;
    const float bb = (c < DMID) ? bm[c] : 0.f;
    float s = 0.f;
#pragma unroll
    for (int r = 0; r < 4; ++r) {
      const int nn = n0 + 4 * lg + r;
      if (nn < NOUT) s += fmaxf(acc[t][r] + bb, 0.f);
    }
    s += __shfl_xor(s, 16, 64);
    s += __shfl_xor(s, 32, 64);
    if (lg == 0) lfeat[wv][c] = s;
  }
  __syncthreads();
  if (tid < DMID)
    part[((size_t)b * 8 + nt) * DMID + tid] =
        lfeat[0][tid] + lfeat[1][tid] + lfeat[2][tid] + lfeat[3][tid];
}

// =====================================================================
// Kernel 6: final readout (unchanged).
// =====================================================================
__global__ void k_head(const float* __restrict__ part, const float* __restrict__ Wo,
                       const float* __restrict__ bo, float* __restrict__ out) {
  const int b = threadIdx.x;  // 64 threads
  float s1 = 0.f;
  for (int c = 0; c < DMID; ++c) {
    float v = 0.f;
    for (int t = 0; t < 8; ++t) v += part[((size_t)b * 8 + t) * DMID + c];
    s1 += v;
  }
  const float mean = s1 / (float)DMID;
  float s2 = 0.f;
  for (int c = 0; c < DMID; ++c) {
    float v = 0.f;
    for (int t = 0; t < 8; ++t) v += part[((size_t)b * 8 + t) * DMID + c];
    const float d = v - mean;
    s2 += d * d;
  }
  const float inv = 1.0f / (sqrtf(s2 / (float)DMID) + 1e-6f);
  float o0 = bo[0], o1 = bo[1];
  for (int c = 0; c < DMID; ++c) {
    float v = 0.f;
    for (int t = 0; t < 8; ++t) v += part[((size_t)b * 8 + t) * DMID + c];
    const float nz = (v - mean) * inv;
    o0 += nz * Wo[c * 2 + 0];
    o1 += nz * Wo[c * 2 + 1];
  }
  out[b * 2 + 0] = o0;
  out[b * 2 + 1] = o1;
}

// =====================================================================
extern "C" void kernel_launch(void* const* d_in, const int* in_sizes, int n_in,
                              void* d_out, int out_size, void* d_ws, size_t ws_size,
                              hipStream_t stream) {
  (void)in_sizes; (void)n_in; (void)out_size;
  const float* x     = (const float*)d_in[0];
  const float* cw    = (const float*)d_in[1];
  const float* gamma = (const float*)d_in[2];
  const float* beta  = (const float*)d_in[3];
  const float* Wq    = (const float*)d_in[4];
  const float* bq    = (const float*)d_in[5];
  const float* Wk    = (const float*)d_in[6];
  const float* bk    = (const float*)d_in[7];
  const float* Wv    = (const float*)d_in[8];
  const float* bv    = (const float*)d_in[9];
  const float* Wm    = (const float*)d_in[10];
  const float* bm    = (const float*)d_in[11];
  const float* Wo    = (const float*)d_in[12];
  const float* bo    = (const float*)d_in[13];
  float* out = (float*)d_out;

  if (ws_size < WS_NEED) return;  // ws too small: fail loudly (poison stays)

  float* wsf = (float*)d_ws;
  float* psum  = wsf + OFF_PSUM;
  float* psq   = wsf + OFF_PSQ;
  float* scale = wsf + OFF_SCALE;
  float* shift = wsf + OFF_SHIFT;
  float* partf = wsf + OFF_PART;
  uint16_t* WTb   = (uint16_t*)((char*)d_ws + BOFF_WT);
  uint16_t* WmT   = (uint16_t*)((char*)d_ws + BOFF_WMT);
  uint16_t* qbuf  = (uint16_t*)((char*)d_ws + BOFF_Q);
  uint16_t* kbuf  = (uint16_t*)((char*)d_ws + BOFF_K);
  uint16_t* vbT   = (uint16_t*)((char*)d_ws + BOFF_VT);
  uint16_t* ymaxT = (uint16_t*)((char*)d_ws + BOFF_YM);
  uint16_t* obuf  = (uint16_t*)((char*)d_ws + BOFF_O);   // aliases ymaxT (dead by then)

  k_prep <<<25, 256, 0, stream>>>(Wq, Wk, Wv, Wm, WTb, WmT);
  k_conv <<<dim3(NB, 16), 512, 0, stream>>>(x, cw, ymaxT, psum, psq);
  k_stats<<<1, NF, 0, stream>>>(psum, psq, gamma, beta, scale, shift);
  k_qkv  <<<dim3(3, 8, NB), 256, 0, stream>>>(ymaxT, scale, shift, WTb, bq, bk, bv,
                                              qbuf, kbuf, vbT);
  k_attn <<<dim3(8, NH, NB), 256, 0, stream>>>(qbuf, kbuf, vbT, obuf);
  k_mhl  <<<dim3(8, NB), 256, 0, stream>>>(obuf, WmT, bm, partf);
  k_head <<<1, NB, 0, stream>>>(partf, Wo, bo, out);
}

// Round 9
// 555.295 us; speedup vs baseline: 1.3812x; 1.3812x over previous
//
#include <hip/hip_runtime.h>
#include <stdint.h>
#include <math.h>

// ---------------- problem sizes ----------------
#define NB   64
#define LL   2000
#define CIN  4
#define NF   256
#define KW   13
#define NOUT 500
#define NH   8
#define DH   64
#define DMID 100
#define NCLS 2

// ---------------- ws layout (byte offsets) ----------------
#define OFF_PSUM   0        // [64][256]
#define OFF_PSQ    16384    // [64][256]
#define OFF_SCALE  32768    // [256]
#define OFF_SHIFT  33024    // [256]
#define OFF_PART   33280    // [64][8][100]
#define BOFF_WT    337920ull                  // W_T bf16 [24][64 d][256 f] = 786,432
#define BOFF_WMT   1124352ull                 // WmT bf16 [112 c][512 k] = 114,688
#define BOFF_Q     1239040ull                 // q bf16 [64][8][500][64] = 32,768,000
#define BOFF_K     34007040ull                // k bf16 same
#define BOFF_VT    66775040ull                // v^T bf16 [64][8][64 d][512 n] = 33,554,432
#define BOFF_YM    100329472ull               // ymax_T / h bf16 [64][500][256] = 16,384,000
#define BOFF_O     BOFF_YM                    // o bf16 [64][500][512] (aliases h span)
#define WS_NEED    133097472ull               // < 128 MiB

// ---------------- bf16 helpers (RNE) ----------------
__device__ __forceinline__ float blo(uint32_t u) { return __uint_as_float(u << 16); }
__device__ __forceinline__ float bhi(uint32_t u) { return __uint_as_float(u & 0xFFFF0000u); }
__device__ __forceinline__ uint32_t f2bf1(float f) {
  uint32_t x = __float_as_uint(f);
  return (x + 0x7FFFu + ((x >> 16) & 1u)) >> 16;
}
__device__ __forceinline__ uint32_t pack2(float a, float b) {
  return f2bf1(a) | (f2bf1(b) << 16);
}

typedef short bf16x8 __attribute__((ext_vector_type(8)));
typedef float f32x4  __attribute__((ext_vector_type(4)));
union UB { uint4 u; bf16x8 v; };

// XOR swizzle for [rows][64 bf16] LDS tiles (128 B rows) — k_attn.
__device__ __forceinline__ int swz(int row, int colElem) {
  return row * 128 + ((colElem * 2) ^ ((row & 7) << 4));
}
// XOR swizzle for [64 n][256 f] bf16 A-tile (512 B rows) — k_qkv.
__device__ __forceinline__ int addrA(int row, int f) {
  return row * 512 + (((f >> 3) ^ (row & 7)) << 4) + ((f & 7) * 2);
}

// =====================================================================
// Kernel 0: weight prep (unchanged).
// =====================================================================
__global__ void k_prep(const float* __restrict__ Wq, const float* __restrict__ Wk,
                       const float* __restrict__ Wv, const float* __restrict__ Wm,
                       uint16_t* __restrict__ WT, uint16_t* __restrict__ WmT) {
  const int g = blockIdx.x;
  if (g < 24) {
    const int which = g >> 3, h = g & 7;
    const float* W = (which == 0 ? Wq : which == 1 ? Wk : Wv) + (size_t)h * NF * DH;
    uint16_t* dst = WT + (size_t)g * DH * NF;
    for (int idx = threadIdx.x; idx < NF * DH; idx += 256) {
      const int f = idx >> 6, d = idx & 63;
      dst[d * NF + f] = (uint16_t)f2bf1(W[idx]);
    }
  } else {
    for (int idx = threadIdx.x; idx < 112 * 512; idx += 256) {
      const int c = idx >> 9, k = idx & 511;
      WmT[idx] = (c < DMID) ? (uint16_t)f2bf1(Wm[k * DMID + c]) : (uint16_t)0;
    }
  }
}

// =====================================================================
// Kernel 1: conv1d + BN partial stats + maxpool(4) (unchanged).
// =====================================================================
__global__ __launch_bounds__(512) void k_conv(const float* __restrict__ x,
                                              const float* __restrict__ cw,
                                              uint16_t* __restrict__ ymaxT,
                                              float* __restrict__ psum,
                                              float* __restrict__ psq) {
  const int b = blockIdx.x;
  const int fg = blockIdx.y;
  const int tid = threadIdx.x;
  const int n = tid;
  const bool act = (n < NOUT);
  const float* xb = x + (size_t)b * (LL * CIN);

  float4 xw[16];
#pragma unroll
  for (int i = 0; i < 16; ++i) {
    const int p = 4 * n - 6 + i;
    if (act && p >= 0 && p < LL)
      xw[i] = *(const float4*)(xb + (size_t)p * CIN);
    else
      xw[i] = make_float4(0.f, 0.f, 0.f, 0.f);
  }

  __shared__ float redS[8][16];
  __shared__ float redQ[8][16];
  const int wave = tid >> 6, lane = tid & 63;
  uint32_t pw[8];
  float prev = 0.f;

  for (int fi = 0; fi < 16; ++fi) {
    const int f = fg * 16 + fi;
    const float* w = cw + (size_t)f * (CIN * KW);
    float wr[4][13];
#pragma unroll
    for (int c = 0; c < 4; ++c)
#pragma unroll
      for (int k = 0; k < 13; ++k) wr[c][k] = w[c * 13 + k];

    float a0 = 0.f, a1 = 0.f, a2 = 0.f, a3 = 0.f;
#pragma unroll
    for (int k = 0; k < 13; ++k) {
      const float4 p0 = xw[k + 0];
      const float4 p1 = xw[k + 1];
      const float4 p2 = xw[k + 2];
      const float4 p3 = xw[k + 3];
      a0 += wr[0][k] * p0.x + wr[1][k] * p0.y + wr[2][k] * p0.z + wr[3][k] * p0.w;
      a1 += wr[0][k] * p1.x + wr[1][k] * p1.y + wr[2][k] * p1.z + wr[3][k] * p1.w;
      a2 += wr[0][k] * p2.x + wr[1][k] * p2.y + wr[2][k] * p2.z + wr[3][k] * p2.w;
      a3 += wr[0][k] * p3.x + wr[1][k] * p3.y + wr[2][k] * p3.z + wr[3][k] * p3.w;
    }
    const float pm = fmaxf(fmaxf(a0, a1), fmaxf(a2, a3));
    if (fi & 1) pw[fi >> 1] = pack2(prev, pm); else prev = pm;

    float s  = act ? (a0 + a1 + a2 + a3) : 0.f;
    float q2 = act ? (a0 * a0 + a1 * a1 + a2 * a2 + a3 * a3) : 0.f;
#pragma unroll
    for (int off = 32; off >= 1; off >>= 1) {
      s  += __shfl_xor(s,  off, 64);
      q2 += __shfl_xor(q2, off, 64);
    }
    if (lane == 0) { redS[wave][fi] = s; redQ[wave][fi] = q2; }
  }
  if (act) {
    uint16_t* dst = ymaxT + ((size_t)b * NOUT + n) * NF + fg * 16;
    uint4 s0 = make_uint4(pw[0], pw[1], pw[2], pw[3]);
    uint4 s1 = make_uint4(pw[4], pw[5], pw[6], pw[7]);
    *(uint4*)dst = s0;
    *(uint4*)(dst + 8) = s1;
  }
  __syncthreads();
  if (tid < 16) {
    float s = 0.f;
#pragma unroll
    for (int wv = 0; wv < 8; ++wv) s += redS[wv][tid];
    psum[b * NF + fg * 16 + tid] = s;
  } else if (tid < 32) {
    float s = 0.f;
#pragma unroll
    for (int wv = 0; wv < 8; ++wv) s += redQ[wv][tid - 16];
    psq[b * NF + fg * 16 + (tid - 16)] = s;
  }
}

// =====================================================================
// Kernel 2: fold BN batch stats into per-channel scale/shift (unchanged).
// =====================================================================
__global__ void k_stats(const float* __restrict__ psum, const float* __restrict__ psq,
                        const float* __restrict__ gamma, const float* __restrict__ beta,
                        float* __restrict__ scale, float* __restrict__ shift) {
  const int f = threadIdx.x;
  float s = 0.f, q = 0.f;
  for (int b = 0; b < NB; ++b) { s += psum[b * NF + f]; q += psq[b * NF + f]; }
  const float inv = 1.0f / (float)(NB * LL);
  const float mean = s * inv;
  const float var = q * inv - mean * mean;
  const float sc = gamma[f] * rsqrtf(var + 1e-5f);
  scale[f] = sc;
  shift[f] = beta[f] - mean * sc;
}

// =====================================================================
// Kernel 2b: in-place BN+ReLU: ymaxT -> h (bf16). Elementwise, grid-stride.
// =====================================================================
__global__ __launch_bounds__(256) void k_bn(uint16_t* __restrict__ ym,
                                            const float* __restrict__ scale,
                                            const float* __restrict__ shift) {
  const int total = NB * NOUT * NF / 8;  // 1,024,000 uint4 vectors
  for (int idx = blockIdx.x * 256 + threadIdx.x; idx < total; idx += gridDim.x * 256) {
    const int f0 = (idx & 31) * 8;
    uint4 u = *(const uint4*)(ym + (size_t)idx * 8);
    const float4 s0 = *(const float4*)(scale + f0);
    const float4 s1 = *(const float4*)(scale + f0 + 4);
    const float4 h0 = *(const float4*)(shift + f0);
    const float4 h1 = *(const float4*)(shift + f0 + 4);
    uint4 o;
    o.x = pack2(fmaxf(s0.x * blo(u.x) + h0.x, 0.f), fmaxf(s0.y * bhi(u.x) + h0.y, 0.f));
    o.y = pack2(fmaxf(s0.z * blo(u.y) + h0.z, 0.f), fmaxf(s0.w * bhi(u.y) + h0.w, 0.f));
    o.z = pack2(fmaxf(s1.x * blo(u.z) + h1.x, 0.f), fmaxf(s1.y * bhi(u.z) + h1.y, 0.f));
    o.w = pack2(fmaxf(s1.z * blo(u.w) + h1.z, 0.f), fmaxf(s1.w * bhi(u.w) + h1.w, 0.f));
    *(uint4*)(ym + (size_t)idx * 8) = o;
  }
}

// =====================================================================
// Kernel 3 (v3): QKV projection, MFMA. grid (3 which, 64 b) = 192 blocks,
// block 512 = 8 waves, wave = one head h=w.  Double-buffered 64x256 h-tile
// in LDS (64 KB, XOR-swizzled).  WT (768 KB) is L2-resident per XCD.
// Stores identical to HW-validated R7 mappings (swapped q/k, normal v).
// =====================================================================
__global__ __launch_bounds__(512, 2) void k_qkv(const uint16_t* __restrict__ hb,
     const uint16_t* __restrict__ WT,
     const float* __restrict__ bq, const float* __restrict__ bk, const float* __restrict__ bv,
     uint16_t* __restrict__ qb, uint16_t* __restrict__ kb, uint16_t* __restrict__ vbT) {
  const int which = blockIdx.x;
  const int b = blockIdx.y;
  const int tid = threadIdx.x;
  const int w = tid >> 6;            // wave index = head
  const int l = tid & 63;
  const int lg = l >> 4, lq = l & 15;

  __shared__ char ldsA[2][32768];

  const uint16_t* WTg = WT + (size_t)(which * 8 + w) * DH * NF;
  const float* biasW = (which == 0 ? bq : which == 1 ? bk : bv) + w * DH;
  uint16_t* outQK = (which == 0 ? qb : kb) + (size_t)(b * NH + w) * NOUT * DH;
  uint16_t* outV  = vbT + (size_t)(b * NH + w) * DH * 512;

  float4 bias4[4];   // q/k epilogue: biasW[16dt+4lg .. +3]
  float biasv[4];    // v   epilogue: biasW[16dt+lq]
#pragma unroll
  for (int dt = 0; dt < 4; ++dt) {
    bias4[dt] = *(const float4*)(biasW + 16 * dt + 4 * lg);
    biasv[dt] = biasW[16 * dt + lq];
  }

  const int srow = tid >> 5;          // 0..15
  const int f0s  = (tid & 31) * 8;
  const uint16_t* hbb = hb + (size_t)b * NOUT * NF;

#define STAGE(buf, nt)                                                        \
  {                                                                           \
    _Pragma("unroll")                                                         \
    for (int p = 0; p < 4; ++p) {                                             \
      const int row = p * 16 + srow;                                          \
      const int n = min((nt) * 64 + row, NOUT - 1);                           \
      const uint4 u = *(const uint4*)(hbb + (size_t)n * NF + f0s);            \
      *(uint4*)(&ldsA[buf][0] + addrA(row, f0s)) = u;                         \
    }                                                                         \
  }

  STAGE(0, 0)
  int cur = 0;
  for (int nt = 0; nt < 8; ++nt) {
    __syncthreads();                 // buf[cur] staged; prev reads of buf[cur^1] done
    if (nt < 7) STAGE(cur ^ 1, nt + 1)
    const int n0 = nt * 64;

    f32x4 acc[4][4] = {};            // q/k: [dt][s] ; v: [s][dt]
#pragma unroll
    for (int c = 0; c < 8; ++c) {
      const int f0 = c * 32 + lg * 8;
      UB wf[4], hf[4];
#pragma unroll
      for (int dt = 0; dt < 4; ++dt)
        wf[dt].u = *(const uint4*)(WTg + (size_t)(16 * dt + lq) * NF + f0);
#pragma unroll
      for (int s = 0; s < 4; ++s)
        hf[s].u = *(const uint4*)(&ldsA[cur][0] + addrA(16 * s + lq, f0));
      if (which < 2) {
#pragma unroll
        for (int dt = 0; dt < 4; ++dt)
#pragma unroll
          for (int s = 0; s < 4; ++s)
            acc[dt][s] = __builtin_amdgcn_mfma_f32_16x16x32_bf16(wf[dt].v, hf[s].v, acc[dt][s], 0, 0, 0);
      } else {
#pragma unroll
        for (int s = 0; s < 4; ++s)
#pragma unroll
          for (int dt = 0; dt < 4; ++dt)
            acc[s][dt] = __builtin_amdgcn_mfma_f32_16x16x32_bf16(hf[s].v, wf[dt].v, acc[s][dt], 0, 0, 0);
      }
    }

    if (which < 2) {
      // D swapped: lane col = n = n0+16s+lq, reg rows = d = 16dt+4lg+r
#pragma unroll
      for (int dt = 0; dt < 4; ++dt) {
        const int d0 = 16 * dt + 4 * lg;
#pragma unroll
        for (int s = 0; s < 4; ++s) {
          const int n = n0 + 16 * s + lq;
          if (n < NOUT) {
            uint2 st;
            st.x = pack2(acc[dt][s][0] + bias4[dt].x, acc[dt][s][1] + bias4[dt].y);
            st.y = pack2(acc[dt][s][2] + bias4[dt].z, acc[dt][s][3] + bias4[dt].w);
            *(uint2*)(outQK + (size_t)n * DH + d0) = st;
          }
        }
      }
    } else {
      // D normal: lane col = d = 16dt+lq, reg rows = n = n0+16s+4lg+r
#pragma unroll
      for (int s = 0; s < 4; ++s) {
        const int nb4 = n0 + 16 * s + 4 * lg;
        if (nb4 < NOUT) {
#pragma unroll
          for (int dt = 0; dt < 4; ++dt) {
            const int d = 16 * dt + lq;
            uint2 st;
            st.x = pack2(acc[s][dt][0] + biasv[dt], acc[s][dt][1] + biasv[dt]);
            st.y = pack2(acc[s][dt][2] + biasv[dt], acc[s][dt][3] + biasv[dt]);
            *(uint2*)(outV + (size_t)d * 512 + nb4) = st;
          }
        }
      }
    }
    cur ^= 1;
  }
#undef STAGE
}

// =====================================================================
// Kernel 4 (v2): fused attention, MFMA flash-style, 128-row q-tiles.
// grid (4 qt, 8 h, 64 b), block 256 = 4 waves; wave owns 32 q-rows as
// two 16-row subtiles (qq).  Per-subtile code = HW-validated R5/R7 path.
// =====================================================================
__global__ __launch_bounds__(256, 2) void k_attn(const uint16_t* __restrict__ qb,
                                                 const uint16_t* __restrict__ kb,
                                                 const uint16_t* __restrict__ vbT,
                                                 uint16_t* __restrict__ ob) {
  const int qt = blockIdx.x;
  const int h  = blockIdx.y;
  const int b  = blockIdx.z;
  const int tid = threadIdx.x;
  const int wv = tid >> 6, l = tid & 63;
  const int lg = l >> 4, lq = l & 15;

  __shared__ char smem[24576];
  char* Ks = smem;                       // K tile  [64 key][64 d] bf16, swizzled
  char* Vs = smem + 8192;                // V^T tile [64 d][64 key] bf16, swizzled
  char* Ps = smem + 16384 + wv * 2048;   // P tile  [16 q][64 key], reused per qq

  const size_t qkbase = (size_t)(b * NH + h) * NOUT * DH;
  const size_t vbase  = (size_t)(b * NH + h) * DH * 512;
  const int q0w = qt * 128 + wv * 32;

  bf16x8 qf[2][2];
#pragma unroll
  for (int qq = 0; qq < 2; ++qq) {
    const int qn = min(q0w + qq * 16 + lq, NOUT - 1);
    const uint16_t* src = qb + qkbase + (size_t)qn * DH + lg * 8;
    UB t0, t1;
    t0.u = *(const uint4*)src;
    t1.u = *(const uint4*)(src + 32);
    qf[qq][0] = t0.v; qf[qq][1] = t1.v;
  }

  f32x4 oacc[2][4] = {};
  float m[2] = {-1e30f, -1e30f};
  float lsum[2] = {0.f, 0.f};

  for (int kt = 0; kt < 8; ++kt) {
    const int kv0 = kt * 64;
    __syncthreads();
    {
      const int r = tid >> 2, cc = (tid & 3) * 16;
      const int kn = min(kv0 + r, NOUT - 1);
      const uint16_t* ksrc = kb + qkbase + (size_t)kn * DH + cc;
      uint4 ka = *(const uint4*)ksrc;
      uint4 kb4 = *(const uint4*)(ksrc + 8);
      *(uint4*)(Ks + swz(r, cc))     = ka;
      *(uint4*)(Ks + swz(r, cc + 8)) = kb4;
      const uint16_t* vsrc = vbT + vbase + (size_t)r * 512 + kv0 + cc;
      uint4 va = *(const uint4*)vsrc;
      uint4 vb4 = *(const uint4*)(vsrc + 8);
      *(uint4*)(Vs + swz(r, cc))     = va;
      *(uint4*)(Vs + swz(r, cc + 8)) = vb4;
    }
    __syncthreads();

#pragma unroll
    for (int qq = 0; qq < 2; ++qq) {
      const int nq = q0w + qq * 16 + lq;

      f32x4 sacc[4] = {};
#pragma unroll
      for (int c = 0; c < 2; ++c)
#pragma unroll
        for (int s = 0; s < 4; ++s) {
          UB kf;
          kf.u = *(const uint4*)(Ks + swz(16 * s + lq, 32 * c + 8 * lg));
          sacc[s] = __builtin_amdgcn_mfma_f32_16x16x32_bf16(kf.v, qf[qq][c], sacc[s], 0, 0, 0);
        }

      float tmax = -1e30f;
#pragma unroll
      for (int s = 0; s < 4; ++s)
#pragma unroll
        for (int r = 0; r < 4; ++r) {
          const int nk = kv0 + 16 * s + 4 * lg + r;
          float val = sacc[s][r] * 0.125f -
                      (4.0f * fabsf((float)(nq - nk)) + 3.0f) * (1.0f / 1999.0f);
          if (nk >= NOUT) val = -1e30f;
          sacc[s][r] = val;
          tmax = fmaxf(tmax, val);
        }
      tmax = fmaxf(tmax, __shfl_xor(tmax, 16, 64));
      tmax = fmaxf(tmax, __shfl_xor(tmax, 32, 64));
      const float mnew = fmaxf(m[qq], tmax);
      const float corr = __expf(m[qq] - mnew);
      m[qq] = mnew;
      float ls = 0.f;
#pragma unroll
      for (int s = 0; s < 4; ++s)
#pragma unroll
        for (int r = 0; r < 4; ++r) {
          const float pv = __expf(sacc[s][r] - mnew);
          sacc[s][r] = pv;
          ls += pv;
        }
      ls += __shfl_xor(ls, 16, 64);
      ls += __shfl_xor(ls, 32, 64);
      lsum[qq] = lsum[qq] * corr + ls;

#pragma unroll
      for (int s = 0; s < 4; ++s) {
        uint2 pw;
        pw.x = pack2(sacc[s][0], sacc[s][1]);
        pw.y = pack2(sacc[s][2], sacc[s][3]);
        *(uint2*)(Ps + swz(lq, 16 * s + 4 * lg)) = pw;
      }

      float cr[4];
#pragma unroll
      for (int r = 0; r < 4; ++r) cr[r] = __shfl(corr, 4 * lg + r, 64);
#pragma unroll
      for (int t = 0; t < 4; ++t)
#pragma unroll
        for (int r = 0; r < 4; ++r) oacc[qq][t][r] *= cr[r];

#pragma unroll
      for (int c = 0; c < 2; ++c) {
        UB pf;
        pf.u = *(const uint4*)(Ps + swz(lq, 32 * c + 8 * lg));
#pragma unroll
        for (int t = 0; t < 4; ++t) {
          UB vf;
          vf.u = *(const uint4*)(Vs + swz(16 * t + lq, 32 * c + 8 * lg));
          oacc[qq][t] = __builtin_amdgcn_mfma_f32_16x16x32_bf16(pf.v, vf.v, oacc[qq][t], 0, 0, 0);
        }
      }
    }
  }

#pragma unroll
  for (int qq = 0; qq < 2; ++qq) {
    const float inv = 1.0f / lsum[qq];
    float invr[4];
#pragma unroll
    for (int r = 0; r < 4; ++r) invr[r] = __shfl(inv, 4 * lg + r, 64);
#pragma unroll
    for (int t = 0; t < 4; ++t) {
      const int d = 16 * t + lq;
#pragma unroll
      for (int r = 0; r < 4; ++r) {
        const int nn = q0w + qq * 16 + 4 * lg + r;
        if (nn < NOUT)
          ob[((size_t)b * NOUT + nn) * (NH * DH) + h * DH + d] =
              (uint16_t)f2bf1(oacc[qq][t][r] * invr[r]);
      }
    }
  }
}

// =====================================================================
// Kernel 5: m = relu(o @ Wm + bm); position-sum -> part (unchanged).
// =====================================================================
__global__ __launch_bounds__(256, 4) void k_mhl(const uint16_t* __restrict__ ob,
                                                const uint16_t* __restrict__ WmT,
                                                const float* __restrict__ bm,
                                                float* __restrict__ part) {
  const int nt = blockIdx.x;
  const int b  = blockIdx.y;
  const int tid = threadIdx.x;
  const int wv = tid >> 6, l = tid & 63;
  const int lg = l >> 4, lq = l & 15;
  const int n0 = nt * 64 + wv * 16;

  __shared__ float lfeat[4][112];

  f32x4 acc[7] = {};
  const int an = min(n0 + lq, NOUT - 1);
  const uint16_t* abase = ob + ((size_t)b * NOUT + an) * (NH * DH);

  for (int kc = 0; kc < 16; ++kc) {
    const int k0 = kc * 32 + lg * 8;
    UB a;
    a.u = *(const uint4*)(abase + k0);
#pragma unroll
    for (int t = 0; t < 7; ++t) {
      UB bfr;
      bfr.u = *(const uint4*)(WmT + (size_t)(16 * t + lq) * 512 + k0);
      acc[t] = __builtin_amdgcn_mfma_f32_16x16x32_bf16(a.v, bfr.v, acc[t], 0, 0, 0);
    }
  }

#pragma unroll
  for (int t = 0; t < 7; ++t) {
    const int c = 16 * t + lq;
    const float bb = (c < DMID) ? bm[c] : 0.f;
    float s = 0.f;
#pragma unroll
    for (int r = 0; r < 4; ++r) {
      const int nn = n0 + 4 * lg + r;
      if (nn < NOUT) s += fmaxf(acc[t][r] + bb, 0.f);
    }
    s += __shfl_xor(s, 16, 64);
    s += __shfl_xor(s, 32, 64);
    if (lg == 0) lfeat[wv][c] = s;
  }
  __syncthreads();
  if (tid < DMID)
    part[((size_t)b * 8 + nt) * DMID + tid] =
        lfeat[0][tid] + lfeat[1][tid] + lfeat[2][tid] + lfeat[3][tid];
}

// =====================================================================
// Kernel 6: final readout (unchanged).
// =====================================================================
__global__ void k_head(const float* __restrict__ part, const float* __restrict__ Wo,
                       const float* __restrict__ bo, float* __restrict__ out) {
  const int b = threadIdx.x;  // 64 threads
  float s1 = 0.f;
  for (int c = 0; c < DMID; ++c) {
    float v = 0.f;
    for (int t = 0; t < 8; ++t) v += part[((size_t)b * 8 + t) * DMID + c];
    s1 += v;
  }
  const float mean = s1 / (float)DMID;
  float s2 = 0.f;
  for (int c = 0; c < DMID; ++c) {
    float v = 0.f;
    for (int t = 0; t < 8; ++t) v += part[((size_t)b * 8 + t) * DMID + c];
    const float d = v - mean;
    s2 += d * d;
  }
  const float inv = 1.0f / (sqrtf(s2 / (float)DMID) + 1e-6f);
  float o0 = bo[0], o1 = bo[1];
  for (int c = 0; c < DMID; ++c) {
    float v = 0.f;
    for (int t = 0; t < 8; ++t) v += part[((size_t)b * 8 + t) * DMID + c];
    const float nz = (v - mean) * inv;
    o0 += nz * Wo[c * 2 + 0];
    o1 += nz * Wo[c * 2 + 1];
  }
  out[b * 2 + 0] = o0;
  out[b * 2 + 1] = o1;
}

// =====================================================================
extern "C" void kernel_launch(void* const* d_in, const int* in_sizes, int n_in,
                              void* d_out, int out_size, void* d_ws, size_t ws_size,
                              hipStream_t stream) {
  (void)in_sizes; (void)n_in; (void)out_size;
  const float* x     = (const float*)d_in[0];
  const float* cw    = (const float*)d_in[1];
  const float* gamma = (const float*)d_in[2];
  const float* beta  = (const float*)d_in[3];
  const float* Wq    = (const float*)d_in[4];
  const float* bq    = (const float*)d_in[5];
  const float* Wk    = (const float*)d_in[6];
  const float* bk    = (const float*)d_in[7];
  const float* Wv    = (const float*)d_in[8];
  const float* bv    = (const float*)d_in[9];
  const float* Wm    = (const float*)d_in[10];
  const float* bm    = (const float*)d_in[11];
  const float* Wo    = (const float*)d_in[12];
  const float* bo    = (const float*)d_in[13];
  float* out = (float*)d_out;

  if (ws_size < WS_NEED) return;  // ws too small: fail loudly (poison stays)

  float* wsf = (float*)d_ws;
  float* psum  = wsf + OFF_PSUM;
  float* psq   = wsf + OFF_PSQ;
  float* scale = wsf + OFF_SCALE;
  float* shift = wsf + OFF_SHIFT;
  float* partf = wsf + OFF_PART;
  uint16_t* WTb   = (uint16_t*)((char*)d_ws + BOFF_WT);
  uint16_t* WmT   = (uint16_t*)((char*)d_ws + BOFF_WMT);
  uint16_t* qbuf  = (uint16_t*)((char*)d_ws + BOFF_Q);
  uint16_t* kbuf  = (uint16_t*)((char*)d_ws + BOFF_K);
  uint16_t* vbT   = (uint16_t*)((char*)d_ws + BOFF_VT);
  uint16_t* ymaxT = (uint16_t*)((char*)d_ws + BOFF_YM);  // becomes h after k_bn
  uint16_t* obuf  = (uint16_t*)((char*)d_ws + BOFF_O);   // aliases h (dead by then)

  k_prep <<<25, 256, 0, stream>>>(Wq, Wk, Wv, Wm, WTb, WmT);
  k_conv <<<dim3(NB, 16), 512, 0, stream>>>(x, cw, ymaxT, psum, psq);
  k_stats<<<1, NF, 0, stream>>>(psum, psq, gamma, beta, scale, shift);
  k_bn   <<<2048, 256, 0, stream>>>(ymaxT, scale, shift);
  k_qkv  <<<dim3(3, NB), 512, 0, stream>>>(ymaxT, WTb, bq, bk, bv, qbuf, kbuf, vbT);
  k_attn <<<dim3(4, NH, NB), 256, 0, stream>>>(qbuf, kbuf, vbT, obuf);
  k_mhl  <<<dim3(8, NB), 256, 0, stream>>>(obuf, WmT, bm, partf);
  k_head <<<1, NB, 0, stream>>>(partf, Wo, bo, out);
}